// Round 1
// baseline (326.053 us; speedup 1.0000x reference)
//
#include <hip/hip_runtime.h>

// Problem constants (from reference)
#define B_Q   4096     // batch (output cols)
#define E_DIM 512      // embedding
#define N_C   2000     // classes
#define PROX  32       // proxies per class
#define N_P   (N_C*PROX) // 64000 weight rows

#define BM 128
#define BN 128
#define BK 32
#define NT (E_DIM/BK)  // 16 K-steps

typedef __bf16 bf16x8 __attribute__((ext_vector_type(8)));
typedef float  f32x4  __attribute__((ext_vector_type(4)));

__device__ __forceinline__ unsigned short f2bf(float f) {
  unsigned u = __builtin_bit_cast(unsigned, f);
  u += 0x7fffu + ((u >> 16) & 1u);          // round-to-nearest-even
  return (unsigned short)(u >> 16);
}

__device__ __forceinline__ void async_ld16(const void* g, void* l) {
  __builtin_amdgcn_global_load_lds(
      (const __attribute__((address_space(1))) void*)g,
      (__attribute__((address_space(3))) void*)l,
      16, 0, 0);
}

// ---------------------------------------------------------------------------
// Row L2-normalize fp32 -> bf16.  One block (128 threads) per 512-elem row.
// ---------------------------------------------------------------------------
__global__ __launch_bounds__(128) void norm_rows_kernel(
    const float* __restrict__ in, unsigned short* __restrict__ outbf)
{
  const int row = blockIdx.x;
  const int tid = threadIdx.x;
  const float4 v = *(const float4*)(in + (size_t)row * E_DIM + tid * 4);
  float ss = v.x*v.x + v.y*v.y + v.z*v.z + v.w*v.w;
  #pragma unroll
  for (int s = 1; s < 64; s <<= 1) ss += __shfl_xor(ss, s);
  __shared__ float partial[2];
  if ((tid & 63) == 0) partial[tid >> 6] = ss;
  __syncthreads();
  const float tot = partial[0] + partial[1];
  const float inv = 1.0f / fmaxf(sqrtf(tot), 1e-12f);
  ushort4 o;
  o.x = f2bf(v.x * inv); o.y = f2bf(v.y * inv);
  o.z = f2bf(v.z * inv); o.w = f2bf(v.w * inv);
  *(ushort4*)(outbf + (size_t)row * E_DIM + tid * 4) = o;
}

// ---------------------------------------------------------------------------
// x = Wn @ Dn^T  (both row-major [rows][512] bf16), fused per-class max over
// consecutive 32-row blocks.  128x128 tile, 4 waves (2x2), 16x16x32 bf16 MFMA,
// double-buffered LDS via global_load_lds(16B).
// ---------------------------------------------------------------------------
__global__ __launch_bounds__(256, 2) void gemm_max_kernel(
    const unsigned short* __restrict__ wbf,   // [64000][512]
    const unsigned short* __restrict__ dbf,   // [4096][512]
    float* __restrict__ out)                  // [2000][4096]
{
  __shared__ __align__(16) unsigned short lds[2][2][BM * BK]; // [buf][A|B]

  const int tid  = threadIdx.x;
  const int lane = tid & 63;
  const int wid  = tid >> 6;
  const int wr   = wid >> 1;   // wave row 0..1 (64 rows each)
  const int wc   = wid & 1;    // wave col 0..1 (64 cols each)

  const int rowBase = blockIdx.y * BM;   // W rows
  const int colBase = blockIdx.x * BN;   // D rows (output cols)

  // Staging: 512 chunks of 16B per tile; thread handles chunks tid, tid+256.
  const int i0 = tid, i1 = tid + 256;
  const unsigned short* gA0 = wbf + (size_t)(rowBase + (i0 >> 2)) * E_DIM + (i0 & 3) * 8;
  const unsigned short* gA1 = wbf + (size_t)(rowBase + (i1 >> 2)) * E_DIM + (i1 & 3) * 8;
  const unsigned short* gB0 = dbf + (size_t)(colBase + (i0 >> 2)) * E_DIM + (i0 & 3) * 8;
  const unsigned short* gB1 = dbf + (size_t)(colBase + (i1 >> 2)) * E_DIM + (i1 & 3) * 8;
  const int l0 = (i0 & ~63) * 8;   // wave-uniform LDS short-offsets
  const int l1 = (i1 & ~63) * 8;

  f32x4 acc[4][4];
  #pragma unroll
  for (int m = 0; m < 4; ++m)
    #pragma unroll
    for (int n = 0; n < 4; ++n)
      acc[m][n] = (f32x4){0.f, 0.f, 0.f, 0.f};

  // prologue: stage tile 0
  {
    async_ld16(gA0, &lds[0][0][l0]);
    async_ld16(gA1, &lds[0][0][l1]);
    async_ld16(gB0, &lds[0][1][l0]);
    async_ld16(gB1, &lds[0][1][l1]);
  }
  __syncthreads();   // compiler drains vmcnt before s_barrier

  const int r  = lane & 15;
  const int kg = lane >> 4;
  const int aoff = (wr * 64 + r) * BK + kg * 8;
  const int boff = (wc * 64 + r) * BK + kg * 8;

  int cur = 0;
  for (int t = 0; t < NT; ++t) {
    if (t + 1 < NT) {
      const int kb = (t + 1) * BK;
      async_ld16(gA0 + kb, &lds[cur ^ 1][0][l0]);
      async_ld16(gA1 + kb, &lds[cur ^ 1][0][l1]);
      async_ld16(gB0 + kb, &lds[cur ^ 1][1][l0]);
      async_ld16(gB1 + kb, &lds[cur ^ 1][1][l1]);
    }
    bf16x8 a[4], b[4];
    #pragma unroll
    for (int m = 0; m < 4; ++m) a[m] = *(const bf16x8*)&lds[cur][0][aoff + m * 16 * BK];
    #pragma unroll
    for (int n = 0; n < 4; ++n) b[n] = *(const bf16x8*)&lds[cur][1][boff + n * 16 * BK];
    #pragma unroll
    for (int m = 0; m < 4; ++m)
      #pragma unroll
      for (int n = 0; n < 4; ++n)
        acc[m][n] = __builtin_amdgcn_mfma_f32_16x16x32_bf16(a[m], b[n], acc[m][n], 0, 0, 0);
    __syncthreads();   // drains vmcnt(0): next buffer staged & all reads done
    cur ^= 1;
  }

  // Epilogue: per-class max.  Wave rows = wr*64 + m*16 + (lane>>4)*4 + j.
  // Class 0 of wave: m in {0,1}; class 1: m in {2,3}.  Reduce across lane>>4.
  const int classBase = (rowBase >> 5) + wr * 2;
  #pragma unroll
  for (int n = 0; n < 4; ++n) {
    float pm0 = -3.4e38f, pm1 = -3.4e38f;
    #pragma unroll
    for (int j = 0; j < 4; ++j) {
      pm0 = fmaxf(pm0, fmaxf(acc[0][n][j], acc[1][n][j]));
      pm1 = fmaxf(pm1, fmaxf(acc[2][n][j], acc[3][n][j]));
    }
    pm0 = fmaxf(pm0, __shfl_xor(pm0, 16));
    pm0 = fmaxf(pm0, __shfl_xor(pm0, 32));
    pm1 = fmaxf(pm1, __shfl_xor(pm1, 16));
    pm1 = fmaxf(pm1, __shfl_xor(pm1, 32));
    const int col = colBase + wc * 64 + n * 16 + r;
    if (lane < 16)       out[(size_t)(classBase + 0) * B_Q + col] = pm0;
    else if (lane < 32)  out[(size_t)(classBase + 1) * B_Q + col] = pm1;
  }
}

// ---------------------------------------------------------------------------
extern "C" void kernel_launch(void* const* d_in, const int* in_sizes, int n_in,
                              void* d_out, int out_size, void* d_ws, size_t ws_size,
                              hipStream_t stream) {
  const float* data = (const float*)d_in[0];   // [4096][512]
  const float* w1   = (const float*)d_in[1];   // [64000][512]
  // d_in[2] segment_ids == arange(P): class = row / 32, implicit.
  float* out = (float*)d_out;                  // [2000][4096]

  unsigned short* wbf = (unsigned short*)d_ws;            // 64000*512 bf16
  unsigned short* dbf = wbf + (size_t)N_P * E_DIM;        // 4096*512 bf16

  norm_rows_kernel<<<N_P, 128, 0, stream>>>(w1, wbf);
  norm_rows_kernel<<<B_Q, 128, 0, stream>>>(data, dbf);
  gemm_max_kernel<<<dim3(B_Q / BN, N_P / BM), 256, 0, stream>>>(wbf, dbf, out);
}

// Round 2
// 287.744 us; speedup vs baseline: 1.1331x; 1.1331x over previous
//
#include <hip/hip_runtime.h>

// Problem constants
#define B_Q   4096
#define E_DIM 512
#define N_C   2000
#define N_P   64000

// GEMM geometry: 256x256 tile, BK=64 (2 K-halves of 32), 8 waves (2M x 4N),
// 8-phase schedule, double-buffered 128 KiB LDS.
#define BM 256
#define BN 256

typedef __bf16 bf16x8 __attribute__((ext_vector_type(8)));
typedef float  f32x4  __attribute__((ext_vector_type(4)));

__device__ __forceinline__ unsigned short f2bf(float f) {
  unsigned u = __builtin_bit_cast(unsigned, f);
  u += 0x7fffu + ((u >> 16) & 1u);
  return (unsigned short)(u >> 16);
}

__device__ __forceinline__ void async_ld16(const void* g, void* l) {
  __builtin_amdgcn_global_load_lds(
      (const __attribute__((address_space(1))) void*)g,
      (__attribute__((address_space(3))) void*)l,
      16, 0, 0);
}

// ---------------------------------------------------------------------------
// Row L2-normalize fp32 -> bf16.  One block (128 threads) per 512-elem row.
// ---------------------------------------------------------------------------
__global__ __launch_bounds__(128) void norm_rows_kernel(
    const float* __restrict__ in, unsigned short* __restrict__ outbf)
{
  const int row = blockIdx.x;
  const int tid = threadIdx.x;
  const float4 v = *(const float4*)(in + (size_t)row * E_DIM + tid * 4);
  float ss = v.x*v.x + v.y*v.y + v.z*v.z + v.w*v.w;
  #pragma unroll
  for (int s = 1; s < 64; s <<= 1) ss += __shfl_xor(ss, s);
  __shared__ float partial[2];
  if ((tid & 63) == 0) partial[tid >> 6] = ss;
  __syncthreads();
  const float tot = partial[0] + partial[1];
  const float inv = 1.0f / fmaxf(sqrtf(tot), 1e-12f);
  ushort4 o;
  o.x = f2bf(v.x * inv); o.y = f2bf(v.y * inv);
  o.z = f2bf(v.z * inv); o.w = f2bf(v.w * inv);
  *(ushort4*)(outbf + (size_t)row * E_DIM + tid * 4) = o;
}

// ---------------------------------------------------------------------------
// 8-phase 256x256 GEMM with fused per-class max epilogue.
//
// LDS layout (bytes):  A[buf][h][row 0..255][chunk 0..3][16B]  base 0
//                      B[buf][h][row 0..255][chunk 0..3][16B]  base 65536
//   region(buf,h) = 16 KiB; buf stride 32768, h stride 16384.
//   chunk swizzle: LDS slot (row, cc) holds global 16B-chunk cc ^ ((row>>1)&3)
//   -> ds_read_b128 at (row, kg^( (row>>1)&3)) spreads lanes 0-15 over all 8
//      4-bank groups (2 lanes/bank = free).  Stager pre-swizzles the GLOBAL
//      source chunk; LDS dest stays linear (global_load_lds requirement).
//
// Region staging ledger (iter computes kt from buf0 ph1-4, kt+1 from buf1
// ph5-8; region = (matrix, khalf) = 2 loads/thread):
//   p1: A(buf1,h1,kt+1)   p2: B(buf1,h1,kt+1)   [read prev p7/p8 -> safe]
//   p3: A(buf0,h0,kt+2)   p4: B(buf0,h0,kt+2)   [read p1/p2      -> safe]
//   p5: A(buf0,h1,kt+2)   p6: B(buf0,h1,kt+2)   [read p3/p4      -> safe]
//   p7: A(buf1,h0,kt+3)   p8: B(buf1,h0,kt+3)   [read p5/p6      -> safe]
// Readiness (vmcnt(8) after even-phase stage, before barrier):
//   p2 wait -> guarantees prev p5,p6 landed (needed by p3 reads of buf0.h1)
//   p4 wait -> prev p7,p8 landed (p5 reads buf1.h0)
//   p6 wait -> cur p1,p2 landed (p7 reads buf1.h1)
//   p8 wait -> cur p3,p4 landed (next p1 reads buf0.h0)
// Prologue: A/B(0,h0,0), A/B(0,h1,0), A/B(1,h0,1) = 12 loads, vmcnt(8).
// Drain iter (kt=6): stages only p1,p2 (tile7.h1); waits 8/4/0.
// ---------------------------------------------------------------------------
#define WAITV(N) asm volatile("s_waitcnt vmcnt(" #N ")" ::: "memory")
#define SBAR     asm volatile("s_barrier" ::: "memory")

#define STAGE_A(BUF,H,KT) do { \
  async_ld16(gA + (KT)*64 + (H)*32,         smem + (BUF)*32768 + (H)*16384 + sdst); \
  async_ld16(gA + 65536 + (KT)*64 + (H)*32, smem + (BUF)*32768 + (H)*16384 + sdst + 8192); \
} while(0)

#define STAGE_B(BUF,H,KT) do { \
  async_ld16(gB + (KT)*64 + (H)*32,         smem + 65536 + (BUF)*32768 + (H)*16384 + sdst); \
  async_ld16(gB + 65536 + (KT)*64 + (H)*32, smem + 65536 + (BUF)*32768 + (H)*16384 + sdst + 8192); \
} while(0)

#define PH(BUF,H,MH,RB, STAGE, WAIT) do { \
  if (RB) { \
    _Pragma("unroll") \
    for (int n = 0; n < 4; ++n) \
      bfr[n] = *(const bf16x8*)(pb + (BUF)*32768 + (H)*16384 + n*1024); \
  } \
  _Pragma("unroll") \
  for (int m = 0; m < 4; ++m) \
    afr[m] = *(const bf16x8*)(pa + (BUF)*32768 + (H)*16384 + ((MH)*4+m)*1024); \
  STAGE; \
  WAIT; \
  SBAR; \
  asm volatile("s_waitcnt lgkmcnt(0)" ::: "memory"); \
  __builtin_amdgcn_sched_barrier(0); \
  __builtin_amdgcn_s_setprio(1); \
  _Pragma("unroll") \
  for (int m = 0; m < 4; ++m) { \
    _Pragma("unroll") \
    for (int n = 0; n < 4; ++n) \
      acc[(MH)*4+m][n] = __builtin_amdgcn_mfma_f32_16x16x32_bf16( \
          afr[m], bfr[n], acc[(MH)*4+m][n], 0, 0, 0); \
  } \
  __builtin_amdgcn_s_setprio(0); \
  SBAR; \
} while(0)

__global__ __launch_bounds__(512, 2) void gemm_max_kernel(
    const unsigned short* __restrict__ wbf,   // [64000][512] bf16, row-normalized
    const unsigned short* __restrict__ dbf,   // [4096][512]  bf16, row-normalized
    float* __restrict__ out)                  // [2000][4096]
{
  extern __shared__ char smem[];              // 131072 B

  const int tid  = threadIdx.x;
  const int lane = tid & 63;
  const int wid  = tid >> 6;      // 0..7
  const int wr   = wid >> 2;      // 0..1  (128 rows each)
  const int wc   = wid & 3;       // 0..3  (64 cols each)

  // XCD-aware swizzle: 4000 blocks, 8 XCDs, 500/chunk (bijective).
  const int bid  = blockIdx.x;
  const int wgid = (bid & 7) * 500 + (bid >> 3);
  const int rowb = wgid >> 4;     // 0..249
  const int colb = wgid & 15;     // 0..15
  const int rowBase = rowb * BM;
  const int colBase = colb * BN;

  // Staging: region = 256 rows x 32 shorts = 1024 x 16B chunks; thread t
  // handles chunks t (rows 0-127) and t+512 (rows 128-255).
  const int srow = tid >> 2;
  const int gch  = (tid & 3) ^ ((tid >> 3) & 3);   // pre-swizzled global chunk
  const unsigned short* gA = wbf + (size_t)(rowBase + srow) * E_DIM + gch * 8;
  const unsigned short* gB = dbf + (size_t)(colBase + srow) * E_DIM + gch * 8;
  const int sdst = tid * 16;      // linear LDS dest (wave-uniform base + lane*16)

  // Fragment read bases (swizzled chunk)
  const int r   = lane & 15;
  const int kg  = lane >> 4;
  const int swz = (kg ^ ((r >> 1) & 3)) * 16;
  const char* pa = smem + (wr * 128 + r) * 64 + swz;
  const char* pb = smem + 65536 + (wc * 64 + r) * 64 + swz;

  f32x4 acc[8][4];
  #pragma unroll
  for (int m = 0; m < 8; ++m)
    #pragma unroll
    for (int n = 0; n < 4; ++n)
      acc[m][n] = (f32x4){0.f, 0.f, 0.f, 0.f};
  bf16x8 afr[4], bfr[4];

  // Prologue: 12 loads, oldest 4 = tile0 h0 (needed by p1).
  STAGE_A(0,0,0); STAGE_B(0,0,0);
  STAGE_A(0,1,0); STAGE_B(0,1,0);
  STAGE_A(1,0,1); STAGE_B(1,0,1);
  WAITV(8);
  SBAR;

  #pragma unroll 1
  for (int kt = 0; kt < 6; kt += 2) {
    PH(0,0,0,1, STAGE_A(1,1,kt+1), (void)0);
    PH(0,0,1,0, STAGE_B(1,1,kt+1), WAITV(8));
    PH(0,1,0,1, STAGE_A(0,0,kt+2), (void)0);
    PH(0,1,1,0, STAGE_B(0,0,kt+2), WAITV(8));
    PH(1,0,0,1, STAGE_A(0,1,kt+2), (void)0);
    PH(1,0,1,0, STAGE_B(0,1,kt+2), WAITV(8));
    PH(1,1,0,1, STAGE_A(1,0,kt+3), (void)0);
    PH(1,1,1,0, STAGE_B(1,0,kt+3), WAITV(8));
  }
  // Drain iteration (kt=6): only tile7.h1 left to stage.
  PH(0,0,0,1, STAGE_A(1,1,7), (void)0);
  PH(0,0,1,0, STAGE_B(1,1,7), WAITV(8));
  PH(0,1,0,1, (void)0, (void)0);
  PH(0,1,1,0, (void)0, WAITV(4));
  PH(1,0,0,1, (void)0, (void)0);
  PH(1,0,1,0, (void)0, WAITV(0));
  PH(1,1,0,1, (void)0, (void)0);
  PH(1,1,1,0, (void)0, (void)0);

  // Epilogue: per-class max.  Wave row = wr*128 + m*16 + kg*4 + j; class
  // within wave = m>>1 (32 rows).  Reduce m-pair x j, then across kg.
  const int classRow = rowb * 8 + wr * 4;
  #pragma unroll
  for (int q = 0; q < 4; ++q) {
    #pragma unroll
    for (int n = 0; n < 4; ++n) {
      float pm = -3.4e38f;
      #pragma unroll
      for (int j = 0; j < 4; ++j)
        pm = fmaxf(pm, fmaxf(acc[2*q][n][j], acc[2*q+1][n][j]));
      pm = fmaxf(pm, __shfl_xor(pm, 16));
      pm = fmaxf(pm, __shfl_xor(pm, 32));
      if (lane < 16)
        out[(size_t)(classRow + q) * B_Q + colBase + wc * 64 + n * 16 + r] = pm;
    }
  }
}

// ---------------------------------------------------------------------------
extern "C" void kernel_launch(void* const* d_in, const int* in_sizes, int n_in,
                              void* d_out, int out_size, void* d_ws, size_t ws_size,
                              hipStream_t stream) {
  const float* data = (const float*)d_in[0];   // [4096][512]
  const float* w1   = (const float*)d_in[1];   // [64000][512]
  float* out = (float*)d_out;                  // [2000][4096]

  unsigned short* wbf = (unsigned short*)d_ws;
  unsigned short* dbf = wbf + (size_t)N_P * E_DIM;

  (void)hipFuncSetAttribute((const void*)gemm_max_kernel,
      hipFuncAttributeMaxDynamicSharedMemorySize, 131072);

  norm_rows_kernel<<<N_P, 128, 0, stream>>>(w1, wbf);
  norm_rows_kernel<<<B_Q, 128, 0, stream>>>(data, dbf);
  gemm_max_kernel<<<4000, 512, 131072, stream>>>(wbf, dbf, out);
}